// Round 9
// baseline (144.134 us; speedup 1.0000x reference)
//
#include <hip/hip_runtime.h>

#define T_SEQ 2048
#define BATCH 4
#define NH 16
#define FDIM 16
#define HDIM 64
#define HIDDEN 1024
#define TOK (BATCH * T_SEQ)      // 8192
#define CH 128
#define NCHUNK (T_SEQ / CH)      // 16
#define NBH (BATCH * NH)         // 64

// workspace offsets (float32 units)
#define QK_OFF   0u              // f32 [TOK, 512]  (Q cols 0..255, K cols 256..511)
#define VT_OFF   4194304u        // bf16 [NBH][64 v][2048 t]
#define SPRE_OFF 16777216u       // bf16 [NBH][NCHUNK][64 n][256 r] (exclusive prefix)
#define MK_OFF   25165824u       // f32 [NBH][NCHUNK][256] (exclusive prefix)
#define OAB_OFF  25427968u       // bf16 [TOK,1024]
#define WQKV_OFF 29622272u       // bf16 [1536,1024] (Wq 0-255, Wk 256-511, Wv 512-1535)
#define WO_OFF   30408704u       // bf16 [1024,1024]
#define HSB_OFF  30932992u       // bf16 [TOK,1024]

typedef float f32x4 __attribute__((ext_vector_type(4)));
typedef short bf16x8 __attribute__((ext_vector_type(8)));
typedef unsigned short us8 __attribute__((ext_vector_type(8)));
typedef unsigned short us4 __attribute__((ext_vector_type(4)));
typedef unsigned int u32;

__device__ __forceinline__ unsigned short f2b(float f) {
  union { float f; unsigned u; } v; v.f = f;
  unsigned r = (v.u + 0x7FFFu + ((v.u >> 16) & 1u)) >> 16;
  return (unsigned short)r;
}
__device__ __forceinline__ float b2f(unsigned short h) {
  union { unsigned u; float f; } v; v.u = ((unsigned)h) << 16; return v.f;
}

__device__ __forceinline__ void gload_lds16(const void* g, void* l) {
  __builtin_amdgcn_global_load_lds(
      (const __attribute__((address_space(1))) u32*)g,
      (__attribute__((address_space(3))) u32*)l, 16, 0, 0);
}

// ---------------------------------------------------------------------------
// One convert kernel: hs -> HSB, Wq|Wk|Wv -> WQKVB, Wo -> WOB. 8 elts/thread.
// ---------------------------------------------------------------------------
__global__ __launch_bounds__(256) void conv_all(const float* __restrict__ hs,
                                                const float* __restrict__ Wq,
                                                const float* __restrict__ Wk,
                                                const float* __restrict__ Wv,
                                                const float* __restrict__ Wo,
                                                unsigned short* __restrict__ HSB,
                                                unsigned short* __restrict__ WQKVB,
                                                unsigned short* __restrict__ WOB) {
  int i = blockIdx.x * 256 + threadIdx.x;
  const float* src;
  unsigned short* dst;
  if (i < 1048576) {
    int f = i * 8; src = hs + f; dst = HSB + f;
  } else if (i < 1245184) {
    int f = (i - 1048576) * 8;
    if (f < 262144)      src = Wq + f;
    else if (f < 524288) src = Wk + (f - 262144);
    else                 src = Wv + (f - 524288);
    dst = WQKVB + f;
  } else {
    int f = (i - 1245184) * 8;
    src = Wo + f; dst = WOB + f;
  }
  float4 v0 = *(const float4*)src, v1 = *(const float4*)(src + 4);
  us8 o;
  o[0] = f2b(v0.x); o[1] = f2b(v0.y); o[2] = f2b(v0.z); o[3] = f2b(v0.w);
  o[4] = f2b(v1.x); o[5] = f2b(v1.y); o[6] = f2b(v1.z); o[7] = f2b(v1.w);
  *(us8*)dst = o;
}

// ---------------------------------------------------------------------------
// GEMM core: BM=BN=128, BK=64, 256 thr (4 waves 2x2). 2-deep LDS (64 KiB ->
// 2 blocks/CU). Counted vmcnt(8), T2 swizzle both-sides, T5 setprio.
// ---------------------------------------------------------------------------
#define LDSA(p) (lds + (p) * 8192)
#define LDSB(p) (lds + 16384 + (p) * 8192)

__device__ __forceinline__ void stage8(const unsigned short* __restrict__ A,
                                       const unsigned short* __restrict__ B,
                                       int m0, int n0, int kt,
                                       unsigned short* lA, unsigned short* lB,
                                       int w, int lrow, int kswz) {
  const int kc = kt * 64 + kswz;
#pragma unroll
  for (int i = 0; i < 4; ++i) {
    int r = w * 32 + i * 8;
    gload_lds16(&A[(size_t)(m0 + r + lrow) * HIDDEN + kc], &lA[r * 64]);
  }
#pragma unroll
  for (int i = 0; i < 4; ++i) {
    int r = w * 32 + i * 8;
    gload_lds16(&B[(size_t)(n0 + r + lrow) * HIDDEN + kc], &lB[r * 64]);
  }
}

#define RD_A(fm, kk) (*(const bf16x8*)&cA[(wm * 64 + (fm) * 16 + ln) * 64 + (((kk) * 32 + lg * 8) ^ swz)])
#define RD_B(fn, kk) (*(const bf16x8*)&cB[(wn * 64 + (fn) * 16 + ln) * 64 + (((kk) * 32 + lg * 8) ^ swz)])

#define GEMM_PIPELINE(Aptr, Bptr)                                              \
  const int tid = threadIdx.x;                                                 \
  const int lane = tid & 63, w = tid >> 6;                                     \
  const int wm = w >> 1, wn = w & 1;                                           \
  const int ln = lane & 15, lg = lane >> 4;                                    \
  const int lrow = lane >> 3;                                                  \
  const int kswz = (((lane & 7) ^ ((lane >> 3) & 7)) * 8);                     \
  const int swz = (ln & 7) << 3;                                               \
  f32x4 acc[4][4];                                                             \
  _Pragma("unroll") for (int m = 0; m < 4; ++m)                                \
    _Pragma("unroll") for (int n = 0; n < 4; ++n)                              \
      acc[m][n] = (f32x4){0.f, 0.f, 0.f, 0.f};                                 \
  stage8(Aptr, Bptr, m0, n0, 0, LDSA(0), LDSB(0), w, lrow, kswz);              \
  stage8(Aptr, Bptr, m0, n0, 1, LDSA(1), LDSB(1), w, lrow, kswz);              \
  asm volatile("s_waitcnt vmcnt(8)" ::: "memory");                             \
  __builtin_amdgcn_s_barrier();                                                \
  _Pragma("unroll 1") for (int t = 0; t < 16; ++t) {                           \
    const unsigned short* cA = LDSA(t & 1);                                    \
    const unsigned short* cB = LDSB(t & 1);                                    \
    bf16x8 af[4][2], bfr[4][2];                                                \
    _Pragma("unroll") for (int f = 0; f < 4; ++f) {                            \
      af[f][0] = RD_A(f, 0); af[f][1] = RD_A(f, 1);                            \
      bfr[f][0] = RD_B(f, 0); bfr[f][1] = RD_B(f, 1);                          \
    }                                                                          \
    asm volatile("s_waitcnt lgkmcnt(0)" ::: "memory");                         \
    __builtin_amdgcn_sched_barrier(0);                                         \
    __builtin_amdgcn_s_barrier();                                              \
    if (t <= 13)                                                               \
      stage8(Aptr, Bptr, m0, n0, t + 2, LDSA(t & 1), LDSB(t & 1), w, lrow, kswz); \
    __builtin_amdgcn_s_setprio(1);                                             \
    _Pragma("unroll") for (int kk = 0; kk < 2; ++kk)                           \
      _Pragma("unroll") for (int fm = 0; fm < 4; ++fm)                         \
        _Pragma("unroll") for (int fn = 0; fn < 4; ++fn)                       \
          acc[fm][fn] = __builtin_amdgcn_mfma_f32_16x16x32_bf16(               \
              af[fm][kk], bfr[fn][kk], acc[fm][fn], 0, 0, 0);                  \
    __builtin_amdgcn_s_setprio(0);                                             \
    if (t <= 13) { asm volatile("s_waitcnt vmcnt(8)" ::: "memory"); }          \
    else if (t == 14) { asm volatile("s_waitcnt vmcnt(0)" ::: "memory"); }     \
    __builtin_amdgcn_s_barrier();                                              \
  }

// ---------------------------------------------------------------------------
// Fused QKV projection: A=HSB [8192,1024], W=WQKVB [1536,1024].
// by 0-3 -> QK f32 [8192,512]; by 4-11 -> V transposed to VTg[bh][v][t].
// Grid 768 = 64 bx * 12 by, bijective XCD swizzle, N-fastest within XCD.
// ---------------------------------------------------------------------------
__global__ __launch_bounds__(256) void proj_gemm(const unsigned short* __restrict__ A,
                                                 const unsigned short* __restrict__ Wb,
                                                 float* __restrict__ QK,
                                                 unsigned short* __restrict__ VTg) {
  __shared__ unsigned short lds[32768];  // 64 KiB
  const int bid = blockIdx.x;
  const int logical = (bid & 7) * 96 + (bid >> 3);  // 768 % 8 == 0
  const int bx = logical / 12, by = logical % 12;
  const int m0 = bx * 128, n0 = by * 128;

  GEMM_PIPELINE(A, Wb)

  if (by < 4) {
    // QK path: f32 row-major [8192, 512]
#pragma unroll
    for (int fm = 0; fm < 4; ++fm)
#pragma unroll
      for (int fn = 0; fn < 4; ++fn) {
        int col = n0 + wn * 64 + fn * 16 + ln;
        int row0 = m0 + wm * 64 + fm * 16 + lg * 4;
#pragma unroll
        for (int j = 0; j < 4; ++j)
          QK[(size_t)(row0 + j) * 512 + col] = acc[fm][fn][j];
      }
  } else {
    // V path: stage transposed tile in LDS, then coalesced 16B stores along t
    unsigned short (*ct)[136] = (unsigned short(*)[136])lds;
#pragma unroll
    for (int fm = 0; fm < 4; ++fm)
#pragma unroll
      for (int fn = 0; fn < 4; ++fn) {
        int cl = wn * 64 + fn * 16 + ln;        // local v col 0..127
        int r0 = wm * 64 + fm * 16 + lg * 4;    // local t row 0..127
        us4 p;
#pragma unroll
        for (int j = 0; j < 4; ++j) p[j] = f2b(acc[fm][fn][j]);
        *(us4*)&ct[cl][r0] = p;
      }
    __builtin_amdgcn_s_barrier();
    asm volatile("" ::: "memory");
    const int vbase = n0 - 512;
    const int b = m0 >> 11, t0 = m0 & 2047;
#pragma unroll
    for (int it = 0; it < 8; ++it) {
      int sid = it * 256 + tid, vl = sid >> 4, tc = sid & 15;
      int vg = vbase + vl, h = vg >> 6, vd = vg & 63;
      us8 val = *(const us8*)&ct[vl][tc * 8];
      *(us8*)&VTg[(((size_t)(b * 16 + h) * 64 + vd) << 11) + t0 + tc * 8] = val;
    }
  }
}

// ---------------------------------------------------------------------------
// Output GEMM: C[8192,1024] f32. Grid 512 = 64 bx * 8 by, XCD-swizzled.
// ---------------------------------------------------------------------------
__global__ __launch_bounds__(256) void out_gemm(const unsigned short* __restrict__ A,
                                                const unsigned short* __restrict__ W,
                                                float* __restrict__ C) {
  __shared__ unsigned short lds[32768];  // 64 KiB
  const int bid = blockIdx.x;
  const int logical = (bid & 7) * 64 + (bid >> 3);  // 512 % 8 == 0
  const int bx = logical >> 3, by = logical & 7;
  const int m0 = bx * 128, n0 = by * 128;

  GEMM_PIPELINE(A, W)

#pragma unroll
  for (int fm = 0; fm < 4; ++fm)
#pragma unroll
    for (int fn = 0; fn < 4; ++fn) {
      int col = n0 + wn * 64 + fn * 16 + ln;
      int row0 = m0 + wm * 64 + fm * 16 + lg * 4;
#pragma unroll
      for (int j = 0; j < 4; ++j)
        C[(size_t)(row0 + j) * 1024 + col] = acc[fm][fn][j];
    }
}

// ---------------------------------------------------------------------------
__device__ __forceinline__ void ln16_reg(float4 a0, float4 a1, float4 a2, float4 a3,
                                         const float* __restrict__ gamma,
                                         const float* __restrict__ beta,
                                         float* dst) {
  float x[16] = {a0.x, a0.y, a0.z, a0.w, a1.x, a1.y, a1.z, a1.w,
                 a2.x, a2.y, a2.z, a2.w, a3.x, a3.y, a3.z, a3.w};
  float mu = 0.f;
#pragma unroll
  for (int f = 0; f < 16; ++f) mu += x[f];
  mu *= 0.0625f;
  float var = 0.f;
#pragma unroll
  for (int f = 0; f < 16; ++f) { float d = x[f] - mu; var += d * d; }
  var *= 0.0625f;
  const float rs = rsqrtf(var + 1e-5f);
#pragma unroll
  for (int f = 0; f < 16; ++f) dst[f] = (x[f] - mu) * rs * gamma[f] + beta[f];
}

__device__ __forceinline__ void ln16(const float* __restrict__ src,
                                     const float* __restrict__ gamma,
                                     const float* __restrict__ beta,
                                     float* dst) {
  float4 a0 = *(const float4*)(src + 0);
  float4 a1 = *(const float4*)(src + 4);
  float4 a2 = *(const float4*)(src + 8);
  float4 a3 = *(const float4*)(src + 12);
  ln16_reg(a0, a1, a2, a3, gamma, beta, dst);
}

// ---------------------------------------------------------------------------
// Fused state-build + exclusive prefix scan (replaces k_states + k_prefix).
// grid (4 vslice, NBH); block walks 16 chunks sequentially, running state
// (256 r x 16 v) in VGPRs (16 f32/thread), writes exclusive prefix bf16 to
// Spre[c] BEFORE accumulating chunk c. vs==0 blocks also do Mk gram+prefix.
// Next-chunk XK/V prefetched to regs before compute (T14).
// ---------------------------------------------------------------------------
__global__ __launch_bounds__(256) void k_state_prefix(const float* __restrict__ QK,
                                                      const unsigned short* __restrict__ VTg,
                                                      const float* __restrict__ gamma,
                                                      const float* __restrict__ beta,
                                                      unsigned short* __restrict__ Spre,
                                                      float* __restrict__ Mk) {
  const int vs = blockIdx.x, bh = blockIdx.y;
  const int b = bh >> 4, h = bh & 15;
  __shared__ float XKT[2][16][140];          // [buf][feature][token]
  __shared__ unsigned short VT[2][16][136];  // [buf][v-local][token]
  const int tid = threadIdx.x;
  const int lane = tid & 63, wid = tid >> 6;
  const int ln = lane & 15, lg = lane >> 4;
  const int vrow = tid >> 4, vcol = (tid & 15) * 8;

  f32x4 state[4];
#pragma unroll
  for (int m = 0; m < 4; ++m) state[m] = (f32x4){0.f, 0.f, 0.f, 0.f};
  float mkrun = 0.f;

  float4 xq0, xq1, xq2, xq3;
  us8 vtr;
  // chunk 0 prefetch
  if (tid < 128) {
    const float* src = QK + (size_t)(b * T_SEQ + tid) * 512 + 256 + h * FDIM;
    xq0 = *(const float4*)(src + 0);  xq1 = *(const float4*)(src + 4);
    xq2 = *(const float4*)(src + 8);  xq3 = *(const float4*)(src + 12);
  }
  vtr = *(const us8*)&VTg[((size_t)bh * 64 + vs * 16 + vrow) * T_SEQ + vcol];
  if (tid < 128) {
    float xr[16];
    ln16_reg(xq0, xq1, xq2, xq3, gamma, beta, xr);
#pragma unroll
    for (int f = 0; f < 16; ++f) XKT[0][f][tid] = xr[f];
  }
  *(us8*)&VT[0][vrow][vcol] = vtr;
  __syncthreads();

  for (int c = 0; c < NCHUNK; ++c) {
    const int pb = c & 1;
    // issue next-chunk global loads (latency hidden under compute below)
    if (c < NCHUNK - 1) {
      if (tid < 128) {
        const float* src = QK + (size_t)(b * T_SEQ + (c + 1) * CH + tid) * 512 + 256 + h * FDIM;
        xq0 = *(const float4*)(src + 0);  xq1 = *(const float4*)(src + 4);
        xq2 = *(const float4*)(src + 8);  xq3 = *(const float4*)(src + 12);
      }
      vtr = *(const us8*)&VTg[((size_t)bh * 64 + vs * 16 + vrow) * T_SEQ + (c + 1) * CH + vcol];
    }

    // exclusive prefix writes (state BEFORE this chunk's contribution)
    unsigned short* Sp = Spre + ((size_t)bh * NCHUNK + c) * (64 * 256);
#pragma unroll
    for (int mi = 0; mi < 4; ++mi) {
      int r0 = (wid * 4 + mi) * 16 + lg * 4;
      us4 pk;
#pragma unroll
      for (int j = 0; j < 4; ++j) pk[j] = f2b(state[mi][j]);
      *(us4*)&Sp[(size_t)(vs * 16 + ln) * 256 + r0] = pk;
    }
    if (vs == 0) Mk[((size_t)bh * NCHUNK + c) * 256 + tid] = mkrun;

    // Mk gram accumulate (f32 exact)
    if (vs == 0) {
      int i = tid >> 4, j = tid & 15;
      float m = 0.f;
#pragma unroll
      for (int cc = 0; cc < CH; ++cc) m += XKT[pb][i][cc] * XKT[pb][j][cc];
      mkrun += m;
    }

    // MFMA accumulate chunk c into running state
#pragma unroll
    for (int kt = 0; kt < 4; ++kt) {
      const int s0 = kt * 32 + lg * 8;
      bf16x8 bfr = *(const bf16x8*)&VT[pb][ln][s0];
#pragma unroll
      for (int mi = 0; mi < 4; ++mi) {
        const int iidx = wid * 4 + mi;
        float4 xi0 = *(const float4*)&XKT[pb][iidx][s0];
        float4 xi1 = *(const float4*)&XKT[pb][iidx][s0 + 4];
        float4 xj0 = *(const float4*)&XKT[pb][ln][s0];
        float4 xj1 = *(const float4*)&XKT[pb][ln][s0 + 4];
        bf16x8 afr;
        afr[0] = (short)f2b(xi0.x * xj0.x); afr[1] = (short)f2b(xi0.y * xj0.y);
        afr[2] = (short)f2b(xi0.z * xj0.z); afr[3] = (short)f2b(xi0.w * xj0.w);
        afr[4] = (short)f2b(xi1.x * xj1.x); afr[5] = (short)f2b(xi1.y * xj1.y);
        afr[6] = (short)f2b(xi1.z * xj1.z); afr[7] = (short)f2b(xi1.w * xj1.w);
        state[mi] = __builtin_amdgcn_mfma_f32_16x16x32_bf16(afr, bfr, state[mi], 0, 0, 0);
      }
    }

    // write next chunk to the other LDS buffer (compiler waits on the loads)
    if (c < NCHUNK - 1) {
      if (tid < 128) {
        float xr[16];
        ln16_reg(xq0, xq1, xq2, xq3, gamma, beta, xr);
#pragma unroll
        for (int f = 0; f < 16; ++f) XKT[pb ^ 1][f][tid] = xr[f];
      }
      *(us8*)&VT[pb ^ 1][vrow][vcol] = vtr;
    }
    __syncthreads();
  }
}

// ---------------------------------------------------------------------------
// Phase 3 (MFMA): att = (XQ XK^T)^2/16 masked; o = att@V + qf@P; z in f32.
// ---------------------------------------------------------------------------
__global__ __launch_bounds__(256) void k_attn_out(const float* __restrict__ QK,
                                                  const unsigned short* __restrict__ VTg,
                                                  const float* __restrict__ gamma,
                                                  const float* __restrict__ beta,
                                                  const unsigned short* __restrict__ Spre,
                                                  const float* __restrict__ Mkp,
                                                  unsigned short* __restrict__ OAB) {
  const int c = blockIdx.x, bh = blockIdx.y;
  const int b = bh >> 4, h = bh & 15;
  __shared__ unsigned short XQb[128][40];
  __shared__ unsigned short XKb[128][40];
  __shared__ unsigned short attb[128 * 128];
  __shared__ unsigned short VT[64][152];
  __shared__ float mksh[256];
  const int tid = threadIdx.x;
  const int lane = tid & 63, wid = tid >> 6;
  const int ln = lane & 15, lg = lane >> 4;

  {
    int r = tid & 127;
    const float* src = QK + (size_t)(b * T_SEQ + c * CH + r) * 512 + (tid < 128 ? 0 : 256) + h * FDIM;
    unsigned short* dst = (tid < 128) ? &XQb[r][0] : &XKb[r][0];
    float xr[16];
    ln16(src, gamma, beta, xr);
    us8 lo, hi, z8;
#pragma unroll
    for (int q = 0; q < 8; ++q) { lo[q] = f2b(xr[q]); hi[q] = f2b(xr[8 + q]); z8[q] = 0; }
    *(us8*)&dst[0] = lo; *(us8*)&dst[8] = hi;
    *(us8*)&dst[16] = z8; *(us8*)&dst[24] = z8;
  }
#pragma unroll
  for (int it = 0; it < 4; ++it) {
    int flat = tid + it * 256; int v = flat >> 4, sb = flat & 15;
    *(us8*)&VT[v][sb * 8] = *(const us8*)&VTg[((size_t)bh * 64 + v) * T_SEQ + c * CH + sb * 8];
  }
  mksh[tid] = Mkp[((size_t)bh * NCHUNK + c) * 256 + tid];
  __syncthreads();

  const int tb = wid * 32;
  const f32x4 zero4 = {0.f, 0.f, 0.f, 0.f};

  bf16x8 aq0 = *(const bf16x8*)&XQb[tb + ln][lg * 8];
  bf16x8 aq1 = *(const bf16x8*)&XQb[tb + 16 + ln][lg * 8];
  float zin[2][4];
#pragma unroll
  for (int mt = 0; mt < 2; ++mt)
#pragma unroll
    for (int j = 0; j < 4; ++j) zin[mt][j] = 0.f;

#pragma unroll
  for (int nt = 0; nt < 8; ++nt) {
    bf16x8 bk = *(const bf16x8*)&XKb[nt * 16 + ln][lg * 8];
    f32x4 c0 = __builtin_amdgcn_mfma_f32_16x16x32_bf16(aq0, bk, zero4, 0, 0, 0);
    f32x4 c1 = __builtin_amdgcn_mfma_f32_16x16x32_bf16(aq1, bk, zero4, 0, 0, 0);
    int s = nt * 16 + ln;
#pragma unroll
    for (int j = 0; j < 4; ++j) {
      int t0 = tb + lg * 4 + j;
      float d0 = c0[j];
      float a0 = (s <= t0) ? d0 * d0 * 0.0625f : 0.f;
      zin[0][j] += a0;
      attb[t0 * 128 + (s ^ ((t0 & 7) << 3))] = f2b(a0);
      int t1 = t0 + 16;
      float d1 = c1[j];
      float a1 = (s <= t1) ? d1 * d1 * 0.0625f : 0.f;
      zin[1][j] += a1;
      attb[t1 * 128 + (s ^ ((t1 & 7) << 3))] = f2b(a1);
    }
  }
#pragma unroll
  for (int mt = 0; mt < 2; ++mt)
#pragma unroll
    for (int j = 0; j < 4; ++j) {
      float zz = zin[mt][j];
      zz += __shfl_xor(zz, 1, 64);
      zz += __shfl_xor(zz, 2, 64);
      zz += __shfl_xor(zz, 4, 64);
      zz += __shfl_xor(zz, 8, 64);
      zin[mt][j] = zz;
    }

  f32x4 o[2][4];
#pragma unroll
  for (int mt = 0; mt < 2; ++mt)
#pragma unroll
    for (int nt = 0; nt < 4; ++nt) o[mt][nt] = zero4;

#pragma unroll
  for (int kt = 0; kt < 4; ++kt) {
    int s0 = kt * 32 + lg * 8;
    bf16x8 a0 = *(const bf16x8*)&attb[(tb + ln) * 128 + (s0 ^ ((ln & 7) << 3))];
    bf16x8 a1 = *(const bf16x8*)&attb[(tb + 16 + ln) * 128 + (s0 ^ ((ln & 7) << 3))];
#pragma unroll
    for (int nt = 0; nt < 4; ++nt) {
      bf16x8 bv = *(const bf16x8*)&VT[nt * 16 + ln][s0];
      o[0][nt] = __builtin_amdgcn_mfma_f32_16x16x32_bf16(a0, bv, o[0][nt], 0, 0, 0);
      o[1][nt] = __builtin_amdgcn_mfma_f32_16x16x32_bf16(a1, bv, o[1][nt], 0, 0, 0);
    }
  }

  const unsigned short* Sp = Spre + ((size_t)bh * NCHUNK + c) * (64 * 256);
  bf16x8 xlo0 = *(const bf16x8*)&XQb[tb + ln][0];
  bf16x8 xhi0 = *(const bf16x8*)&XQb[tb + ln][8];
  bf16x8 xlo1 = *(const bf16x8*)&XQb[tb + 16 + ln][0];
  bf16x8 xhi1 = *(const bf16x8*)&XQb[tb + 16 + ln][8];
#pragma unroll
  for (int kt = 0; kt < 8; ++kt) {
    int i = kt * 2 + (lg >> 1);
    float xqi0 = b2f(XQb[tb + ln][i]) * 0.0625f;
    float xqi1 = b2f(XQb[tb + 16 + ln][i]) * 0.0625f;
    bf16x8 sel0 = (lg & 1) ? xhi0 : xlo0;
    bf16x8 sel1 = (lg & 1) ? xhi1 : xlo1;
    bf16x8 qa0, qa1;
#pragma unroll
    for (int jj = 0; jj < 8; ++jj) {
      qa0[jj] = (short)f2b(xqi0 * b2f((unsigned short)sel0[jj]));
      qa1[jj] = (short)f2b(xqi1 * b2f((unsigned short)sel1[jj]));
    }
    int r0 = kt * 32 + lg * 8;
#pragma unroll
    for (int nt = 0; nt < 4; ++nt) {
      bf16x8 bp = *(const bf16x8*)&Sp[(size_t)(nt * 16 + ln) * 256 + r0];
      o[0][nt] = __builtin_amdgcn_mfma_f32_16x16x32_bf16(qa0, bp, o[0][nt], 0, 0, 0);
      o[1][nt] = __builtin_amdgcn_mfma_f32_16x16x32_bf16(qa1, bp, o[1][nt], 0, 0, 0);
    }
  }

  float zi2[2][4];
#pragma unroll
  for (int mt = 0; mt < 2; ++mt)
#pragma unroll
    for (int j = 0; j < 4; ++j) {
      int t = tb + mt * 16 + lg * 4 + j;
      float xqi = b2f(XQb[t][ln]);
      float p = 0.f;
#pragma unroll
      for (int jm = 0; jm < 16; ++jm) p += b2f(XQb[t][jm]) * mksh[jm * 16 + ln];
      p *= xqi;
      p += __shfl_xor(p, 1, 64);
      p += __shfl_xor(p, 2, 64);
      p += __shfl_xor(p, 4, 64);
      p += __shfl_xor(p, 8, 64);
      zi2[mt][j] = p * 0.0625f;
    }

  unsigned short* ob = OAB + ((size_t)(b * T_SEQ + c * CH)) * 1024 + h * 64;
#pragma unroll
  for (int mt = 0; mt < 2; ++mt)
#pragma unroll
    for (int j = 0; j < 4; ++j) {
      int t = tb + mt * 16 + lg * 4 + j;
      float inv = 1.0f / (zin[mt][j] + zi2[mt][j] + 1e-10f);
#pragma unroll
      for (int nt = 0; nt < 4; ++nt)
        ob[(size_t)t * 1024 + nt * 16 + ln] = f2b(o[mt][nt][j] * inv);
    }
}

// ---------------------------------------------------------------------------
extern "C" void kernel_launch(void* const* d_in, const int* in_sizes, int n_in,
                              void* d_out, int out_size, void* d_ws, size_t ws_size,
                              hipStream_t stream) {
  const float* hs    = (const float*)d_in[0];
  const float* Wq    = (const float*)d_in[1];
  const float* Wk    = (const float*)d_in[2];
  const float* Wv    = (const float*)d_in[3];
  const float* Wo    = (const float*)d_in[4];
  const float* gamma = (const float*)d_in[5];
  const float* beta  = (const float*)d_in[6];
  float* out = (float*)d_out;
  float* ws  = (float*)d_ws;

  float* QK = ws + QK_OFF;
  unsigned short* VTg   = (unsigned short*)(ws + VT_OFF);
  unsigned short* Spre  = (unsigned short*)(ws + SPRE_OFF);
  float* Mk = ws + MK_OFF;
  unsigned short* OAB   = (unsigned short*)(ws + OAB_OFF);
  unsigned short* WQKVB = (unsigned short*)(ws + WQKV_OFF);
  unsigned short* WOB   = (unsigned short*)(ws + WO_OFF);
  unsigned short* HSB   = (unsigned short*)(ws + HSB_OFF);

  dim3 blk(256);
  conv_all<<<5376, blk, 0, stream>>>(hs, Wq, Wk, Wv, Wo, HSB, WQKVB, WOB);
  proj_gemm<<<768, blk, 0, stream>>>(HSB, WQKVB, QK, VTg);
  k_state_prefix<<<dim3(4, NBH), blk, 0, stream>>>(QK, VTg, gamma, beta, Spre, Mk);
  k_attn_out<<<dim3(NCHUNK, NBH), blk, 0, stream>>>(QK, VTg, gamma, beta, Spre, Mk, OAB);
  out_gemm<<<512, blk, 0, stream>>>(OAB, WOB, out);
}

// Round 10
// 125.315 us; speedup vs baseline: 1.1502x; 1.1502x over previous
//
#include <hip/hip_runtime.h>

#define T_SEQ 2048
#define BATCH 4
#define NH 16
#define FDIM 16
#define HDIM 64
#define HIDDEN 1024
#define TOK (BATCH * T_SEQ)      // 8192
#define CH 128
#define NCHUNK (T_SEQ / CH)      // 16
#define NBH (BATCH * NH)         // 64

// workspace offsets (float32 units)
#define QK_OFF   0u              // f32 [TOK, 512]  (Q cols 0..255, K cols 256..511)
#define VT_OFF   4194304u        // bf16 [NBH][64 v][2048 t]
#define SRAW_OFF 8388608u        // bf16 [NBH][NCHUNK][64 n][256 r] (linear)
#define SPRE_OFF 16777216u       // bf16 same extent, XOR-swizzled (r ^= (n&7)<<3)
#define MK_OFF   25165824u       // f32 [NBH][NCHUNK][256] (exclusive prefix)
#define OAB_OFF  25427968u       // bf16 [TOK,1024]
#define WQKV_OFF 29622272u       // bf16 [1536,1024] (Wq 0-255, Wk 256-511, Wv 512-1535)
#define WO_OFF   30408704u       // bf16 [1024,1024]
#define HSB_OFF  30932992u       // bf16 [TOK,1024]

typedef float f32x4 __attribute__((ext_vector_type(4)));
typedef short bf16x8 __attribute__((ext_vector_type(8)));
typedef unsigned short us8 __attribute__((ext_vector_type(8)));
typedef unsigned short us4 __attribute__((ext_vector_type(4)));
typedef unsigned int u32;

__device__ __forceinline__ unsigned short f2b(float f) {
  union { float f; unsigned u; } v; v.f = f;
  unsigned r = (v.u + 0x7FFFu + ((v.u >> 16) & 1u)) >> 16;
  return (unsigned short)r;
}
__device__ __forceinline__ float b2f(unsigned short h) {
  union { unsigned u; float f; } v; v.u = ((unsigned)h) << 16; return v.f;
}

__device__ __forceinline__ void gload_lds16(const void* g, void* l) {
  __builtin_amdgcn_global_load_lds(
      (const __attribute__((address_space(1))) u32*)g,
      (__attribute__((address_space(3))) u32*)l, 16, 0, 0);
}

// ---------------------------------------------------------------------------
// One convert kernel: hs -> HSB, Wq|Wk|Wv -> WQKVB, Wo -> WOB. 8 elts/thread.
// ---------------------------------------------------------------------------
__global__ __launch_bounds__(256) void conv_all(const float* __restrict__ hs,
                                                const float* __restrict__ Wq,
                                                const float* __restrict__ Wk,
                                                const float* __restrict__ Wv,
                                                const float* __restrict__ Wo,
                                                unsigned short* __restrict__ HSB,
                                                unsigned short* __restrict__ WQKVB,
                                                unsigned short* __restrict__ WOB) {
  int i = blockIdx.x * 256 + threadIdx.x;
  const float* src;
  unsigned short* dst;
  if (i < 1048576) {
    int f = i * 8; src = hs + f; dst = HSB + f;
  } else if (i < 1245184) {
    int f = (i - 1048576) * 8;
    if (f < 262144)      src = Wq + f;
    else if (f < 524288) src = Wk + (f - 262144);
    else                 src = Wv + (f - 524288);
    dst = WQKVB + f;
  } else {
    int f = (i - 1245184) * 8;
    src = Wo + f; dst = WOB + f;
  }
  float4 v0 = *(const float4*)src, v1 = *(const float4*)(src + 4);
  us8 o;
  o[0] = f2b(v0.x); o[1] = f2b(v0.y); o[2] = f2b(v0.z); o[3] = f2b(v0.w);
  o[4] = f2b(v1.x); o[5] = f2b(v1.y); o[6] = f2b(v1.z); o[7] = f2b(v1.w);
  *(us8*)dst = o;
}

// ---------------------------------------------------------------------------
// GEMM core: BM=BN=128, BK=64, 256 thr (4 waves 2x2). 2-deep LDS (64 KiB ->
// 2 blocks/CU). Counted vmcnt(8), T2 swizzle both-sides, T5 setprio.
// ---------------------------------------------------------------------------
#define LDSA(p) (lds + (p) * 8192)
#define LDSB(p) (lds + 16384 + (p) * 8192)

__device__ __forceinline__ void stage8(const unsigned short* __restrict__ A,
                                       const unsigned short* __restrict__ B,
                                       int m0, int n0, int kt,
                                       unsigned short* lA, unsigned short* lB,
                                       int w, int lrow, int kswz) {
  const int kc = kt * 64 + kswz;
#pragma unroll
  for (int i = 0; i < 4; ++i) {
    int r = w * 32 + i * 8;
    gload_lds16(&A[(size_t)(m0 + r + lrow) * HIDDEN + kc], &lA[r * 64]);
  }
#pragma unroll
  for (int i = 0; i < 4; ++i) {
    int r = w * 32 + i * 8;
    gload_lds16(&B[(size_t)(n0 + r + lrow) * HIDDEN + kc], &lB[r * 64]);
  }
}

#define RD_A(fm, kk) (*(const bf16x8*)&cA[(wm * 64 + (fm) * 16 + ln) * 64 + (((kk) * 32 + lg * 8) ^ swz)])
#define RD_B(fn, kk) (*(const bf16x8*)&cB[(wn * 64 + (fn) * 16 + ln) * 64 + (((kk) * 32 + lg * 8) ^ swz)])

#define GEMM_PIPELINE(Aptr, Bptr)                                              \
  const int tid = threadIdx.x;                                                 \
  const int lane = tid & 63, w = tid >> 6;                                     \
  const int wm = w >> 1, wn = w & 1;                                           \
  const int ln = lane & 15, lg = lane >> 4;                                    \
  const int lrow = lane >> 3;                                                  \
  const int kswz = (((lane & 7) ^ ((lane >> 3) & 7)) * 8);                     \
  const int swz = (ln & 7) << 3;                                               \
  f32x4 acc[4][4];                                                             \
  _Pragma("unroll") for (int m = 0; m < 4; ++m)                                \
    _Pragma("unroll") for (int n = 0; n < 4; ++n)                              \
      acc[m][n] = (f32x4){0.f, 0.f, 0.f, 0.f};                                 \
  stage8(Aptr, Bptr, m0, n0, 0, LDSA(0), LDSB(0), w, lrow, kswz);              \
  stage8(Aptr, Bptr, m0, n0, 1, LDSA(1), LDSB(1), w, lrow, kswz);              \
  asm volatile("s_waitcnt vmcnt(8)" ::: "memory");                             \
  __builtin_amdgcn_s_barrier();                                                \
  _Pragma("unroll 1") for (int t = 0; t < 16; ++t) {                           \
    const unsigned short* cA = LDSA(t & 1);                                    \
    const unsigned short* cB = LDSB(t & 1);                                    \
    bf16x8 af[4][2], bfr[4][2];                                                \
    _Pragma("unroll") for (int f = 0; f < 4; ++f) {                            \
      af[f][0] = RD_A(f, 0); af[f][1] = RD_A(f, 1);                            \
      bfr[f][0] = RD_B(f, 0); bfr[f][1] = RD_B(f, 1);                          \
    }                                                                          \
    asm volatile("s_waitcnt lgkmcnt(0)" ::: "memory");                         \
    __builtin_amdgcn_sched_barrier(0);                                         \
    __builtin_amdgcn_s_barrier();                                              \
    if (t <= 13)                                                               \
      stage8(Aptr, Bptr, m0, n0, t + 2, LDSA(t & 1), LDSB(t & 1), w, lrow, kswz); \
    __builtin_amdgcn_s_setprio(1);                                             \
    _Pragma("unroll") for (int kk = 0; kk < 2; ++kk)                           \
      _Pragma("unroll") for (int fm = 0; fm < 4; ++fm)                         \
        _Pragma("unroll") for (int fn = 0; fn < 4; ++fn)                       \
          acc[fm][fn] = __builtin_amdgcn_mfma_f32_16x16x32_bf16(               \
              af[fm][kk], bfr[fn][kk], acc[fm][fn], 0, 0, 0);                  \
    __builtin_amdgcn_s_setprio(0);                                             \
    if (t <= 13) { asm volatile("s_waitcnt vmcnt(8)" ::: "memory"); }          \
    else if (t == 14) { asm volatile("s_waitcnt vmcnt(0)" ::: "memory"); }     \
    __builtin_amdgcn_s_barrier();                                              \
  }

// ---------------------------------------------------------------------------
// Fused QKV projection: A=HSB [8192,1024], W=WQKVB [1536,1024].
// by 0-3 -> QK f32 [8192,512]; by 4-11 -> V transposed to VTg[bh][v][t].
// Grid 768 = 64 bx * 12 by, bijective XCD swizzle, N-fastest within XCD.
// ---------------------------------------------------------------------------
__global__ __launch_bounds__(256) void proj_gemm(const unsigned short* __restrict__ A,
                                                 const unsigned short* __restrict__ Wb,
                                                 float* __restrict__ QK,
                                                 unsigned short* __restrict__ VTg) {
  __shared__ unsigned short lds[32768];  // 64 KiB
  const int bid = blockIdx.x;
  const int logical = (bid & 7) * 96 + (bid >> 3);  // 768 % 8 == 0
  const int bx = logical / 12, by = logical % 12;
  const int m0 = bx * 128, n0 = by * 128;

  GEMM_PIPELINE(A, Wb)

  if (by < 4) {
    // QK path: f32 row-major [8192, 512]
#pragma unroll
    for (int fm = 0; fm < 4; ++fm)
#pragma unroll
      for (int fn = 0; fn < 4; ++fn) {
        int col = n0 + wn * 64 + fn * 16 + ln;
        int row0 = m0 + wm * 64 + fm * 16 + lg * 4;
#pragma unroll
        for (int j = 0; j < 4; ++j)
          QK[(size_t)(row0 + j) * 512 + col] = acc[fm][fn][j];
      }
  } else {
    // V path: stage transposed tile in LDS, then coalesced 16B stores along t
    unsigned short (*ct)[136] = (unsigned short(*)[136])lds;
#pragma unroll
    for (int fm = 0; fm < 4; ++fm)
#pragma unroll
      for (int fn = 0; fn < 4; ++fn) {
        int cl = wn * 64 + fn * 16 + ln;        // local v col 0..127
        int r0 = wm * 64 + fm * 16 + lg * 4;    // local t row 0..127
        us4 p;
#pragma unroll
        for (int j = 0; j < 4; ++j) p[j] = f2b(acc[fm][fn][j]);
        *(us4*)&ct[cl][r0] = p;
      }
    __builtin_amdgcn_s_barrier();
    asm volatile("" ::: "memory");
    const int vbase = n0 - 512;
    const int b = m0 >> 11, t0 = m0 & 2047;
#pragma unroll
    for (int it = 0; it < 8; ++it) {
      int sid = it * 256 + tid, vl = sid >> 4, tc = sid & 15;
      int vg = vbase + vl, h = vg >> 6, vd = vg & 63;
      us8 val = *(const us8*)&ct[vl][tc * 8];
      *(us8*)&VTg[(((size_t)(b * 16 + h) * 64 + vd) << 11) + t0 + tc * 8] = val;
    }
  }
}

// ---------------------------------------------------------------------------
// Output GEMM: C[8192,1024] f32. Grid 512 = 64 bx * 8 by, XCD-swizzled.
// ---------------------------------------------------------------------------
__global__ __launch_bounds__(256) void out_gemm(const unsigned short* __restrict__ A,
                                                const unsigned short* __restrict__ W,
                                                float* __restrict__ C) {
  __shared__ unsigned short lds[32768];  // 64 KiB
  const int bid = blockIdx.x;
  const int logical = (bid & 7) * 64 + (bid >> 3);  // 512 % 8 == 0
  const int bx = logical >> 3, by = logical & 7;
  const int m0 = bx * 128, n0 = by * 128;

  GEMM_PIPELINE(A, W)

#pragma unroll
  for (int fm = 0; fm < 4; ++fm)
#pragma unroll
    for (int fn = 0; fn < 4; ++fn) {
      int col = n0 + wn * 64 + fn * 16 + ln;
      int row0 = m0 + wm * 64 + fm * 16 + lg * 4;
#pragma unroll
      for (int j = 0; j < 4; ++j)
        C[(size_t)(row0 + j) * 1024 + col] = acc[fm][fn][j];
    }
}

// ---------------------------------------------------------------------------
__device__ __forceinline__ void ln16(const float* __restrict__ src,
                                     const float* __restrict__ gamma,
                                     const float* __restrict__ beta,
                                     float* dst) {
  float x[16];
#pragma unroll
  for (int q = 0; q < 4; ++q) {
    float4 v = *(const float4*)(src + q * 4);
    x[q * 4 + 0] = v.x; x[q * 4 + 1] = v.y;
    x[q * 4 + 2] = v.z; x[q * 4 + 3] = v.w;
  }
  float mu = 0.f;
#pragma unroll
  for (int f = 0; f < 16; ++f) mu += x[f];
  mu *= 0.0625f;
  float var = 0.f;
#pragma unroll
  for (int f = 0; f < 16; ++f) { float d = x[f] - mu; var += d * d; }
  var *= 0.0625f;
  const float rs = rsqrtf(var + 1e-5f);
#pragma unroll
  for (int f = 0; f < 16; ++f) dst[f] = (x[f] - mu) * rs * gamma[f] + beta[f];
}

// ---------------------------------------------------------------------------
// Phase 1 (MFMA): S_raw_T[n][r] = sum_s kf[s][r] * V[s][n];  Mk gram (f32).
// ---------------------------------------------------------------------------
__global__ __launch_bounds__(256) void k_states(const float* __restrict__ QK,
                                                const unsigned short* __restrict__ VTg,
                                                const float* __restrict__ gamma,
                                                const float* __restrict__ beta,
                                                unsigned short* __restrict__ Sraw,
                                                float* __restrict__ Mk) {
  const int c = blockIdx.x, bh = blockIdx.y;
  const int b = bh >> 4, h = bh & 15;
  __shared__ float XKT[16][140];
  __shared__ unsigned short VT[64][152];
  const int tid = threadIdx.x;
  const int lane = tid & 63, wid = tid >> 6;
  const int ln = lane & 15, lg = lane >> 4;

  if (tid < 128) {
    float xr[16];
    ln16(QK + (size_t)(b * T_SEQ + c * CH + tid) * 512 + 256 + h * FDIM, gamma, beta, xr);
#pragma unroll
    for (int f = 0; f < 16; ++f) XKT[f][tid] = xr[f];
  }
#pragma unroll
  for (int it = 0; it < 4; ++it) {
    int flat = tid + it * 256; int v = flat >> 4, sb = flat & 15;
    *(us8*)&VT[v][sb * 8] = *(const us8*)&VTg[((size_t)bh * 64 + v) * T_SEQ + c * CH + sb * 8];
  }
  __syncthreads();

  {
    int i = tid >> 4, j = tid & 15;
    float m = 0.f;
    for (int cc = 0; cc < CH; ++cc) m += XKT[i][cc] * XKT[j][cc];
    Mk[((size_t)bh * NCHUNK + c) * 256 + tid] = m;
  }

  f32x4 acc[4][4];
#pragma unroll
  for (int m = 0; m < 4; ++m)
#pragma unroll
    for (int n = 0; n < 4; ++n) acc[m][n] = (f32x4){0.f, 0.f, 0.f, 0.f};

#pragma unroll
  for (int kt = 0; kt < 4; ++kt) {
    const int s0 = kt * 32 + lg * 8;
    bf16x8 bfr[4];
#pragma unroll
    for (int nt = 0; nt < 4; ++nt) bfr[nt] = *(const bf16x8*)&VT[nt * 16 + ln][s0];
#pragma unroll
    for (int mi = 0; mi < 4; ++mi) {
      const int iidx = wid * 4 + mi;
      float4 xi0 = *(const float4*)&XKT[iidx][s0];
      float4 xi1 = *(const float4*)&XKT[iidx][s0 + 4];
      float4 xj0 = *(const float4*)&XKT[ln][s0];
      float4 xj1 = *(const float4*)&XKT[ln][s0 + 4];
      bf16x8 afr;
      afr[0] = (short)f2b(xi0.x * xj0.x); afr[1] = (short)f2b(xi0.y * xj0.y);
      afr[2] = (short)f2b(xi0.z * xj0.z); afr[3] = (short)f2b(xi0.w * xj0.w);
      afr[4] = (short)f2b(xi1.x * xj1.x); afr[5] = (short)f2b(xi1.y * xj1.y);
      afr[6] = (short)f2b(xi1.z * xj1.z); afr[7] = (short)f2b(xi1.w * xj1.w);
#pragma unroll
      for (int nt = 0; nt < 4; ++nt)
        acc[mi][nt] = __builtin_amdgcn_mfma_f32_16x16x32_bf16(afr, bfr[nt], acc[mi][nt], 0, 0, 0);
    }
  }

  unsigned short* Sp = Sraw + ((size_t)bh * NCHUNK + c) * (64 * 256);
#pragma unroll
  for (int mi = 0; mi < 4; ++mi) {
    int r0 = (wid * 4 + mi) * 16 + lg * 4;
#pragma unroll
    for (int nt = 0; nt < 4; ++nt) {
      int n = nt * 16 + ln;
      us4 pk;
#pragma unroll
      for (int j = 0; j < 4; ++j) pk[j] = f2b(acc[mi][nt][j]);
      *(us4*)&Sp[(size_t)n * 256 + r0] = pk;
    }
  }
}

// ---------------------------------------------------------------------------
// Phase 2 merged: blockIdx.x<8 -> S prefix (writes Spre XOR-SWIZZLED:
// elem (n,r) stored at n*256 + (r ^ ((n&7)<<3))); ==8 -> Mk prefix.
// ---------------------------------------------------------------------------
__global__ __launch_bounds__(256) void k_prefix(const unsigned short* __restrict__ Sraw,
                                                unsigned short* __restrict__ Spre,
                                                float* __restrict__ Mk) {
  const int bh = blockIdx.y;
  if (blockIdx.x < 8) {
    const int e8 = blockIdx.x * 256 + threadIdx.x;  // < 2048 (8-elem units)
    const int n = (e8 * 8) >> 8, r = (e8 * 8) & 255;
    const int rsw = r ^ ((n & 7) << 3);             // aligned-8 XOR, stays in [0,256)
    size_t rbase = (size_t)bh * NCHUNK * 16384 + (size_t)e8 * 8;
    size_t wbase = (size_t)bh * NCHUNK * 16384 + (size_t)n * 256 + rsw;
    float run[8] = {0.f, 0.f, 0.f, 0.f, 0.f, 0.f, 0.f, 0.f};
    for (int cc = 0; cc < NCHUNK; ++cc) {
      us8 v = *(const us8*)&Sraw[rbase + (size_t)cc * 16384];
      us8 w;
#pragma unroll
      for (int q = 0; q < 8; ++q) w[q] = f2b(run[q]);
      *(us8*)&Spre[wbase + (size_t)cc * 16384] = w;
#pragma unroll
      for (int q = 0; q < 8; ++q) run[q] += b2f(v[q]);
    }
  } else {
    const int e = threadIdx.x;
    size_t base = (size_t)bh * NCHUNK * 256 + e;
    float run = 0.f;
    for (int c = 0; c < NCHUNK; ++c) {
      float v = Mk[base + (size_t)c * 256];
      Mk[base + (size_t)c * 256] = run;
      run += v;
    }
  }
}

// ---------------------------------------------------------------------------
// Phase 3 (MFMA): inter (staged swizzled Sp in LDS) FIRST, then att, then PV.
// ---------------------------------------------------------------------------
__global__ __launch_bounds__(256) void k_attn_out(const float* __restrict__ QK,
                                                  const unsigned short* __restrict__ VTg,
                                                  const float* __restrict__ gamma,
                                                  const float* __restrict__ beta,
                                                  const unsigned short* __restrict__ Spre,
                                                  const float* __restrict__ Mkp,
                                                  unsigned short* __restrict__ OAB) {
  const int c = blockIdx.x, bh = blockIdx.y;
  const int b = bh >> 4, h = bh & 15;
  __shared__ unsigned short XQb[128][40];
  __shared__ unsigned short XKb[128][40];
  __shared__ unsigned short attb[128 * 128];  // holds Sp (swizzled) then att
  __shared__ unsigned short VT[64][152];
  __shared__ float mksh[256];
  const int tid = threadIdx.x;
  const int lane = tid & 63, wid = tid >> 6;
  const int ln = lane & 15, lg = lane >> 4;

  {
    int r = tid & 127;
    const float* src = QK + (size_t)(b * T_SEQ + c * CH + r) * 512 + (tid < 128 ? 0 : 256) + h * FDIM;
    unsigned short* dst = (tid < 128) ? &XQb[r][0] : &XKb[r][0];
    float xr[16];
    ln16(src, gamma, beta, xr);
    us8 lo, hi, z8;
#pragma unroll
    for (int q = 0; q < 8; ++q) { lo[q] = f2b(xr[q]); hi[q] = f2b(xr[8 + q]); z8[q] = 0; }
    *(us8*)&dst[0] = lo; *(us8*)&dst[8] = hi;
    *(us8*)&dst[16] = z8; *(us8*)&dst[24] = z8;
  }
  // stage swizzled Sp (32 KB) into attb via coalesced global_load_lds
  {
    const unsigned short* Spg = Spre + ((size_t)bh * NCHUNK + c) * (64 * 256);
#pragma unroll
    for (int it = 0; it < 8; ++it) {
      int seg = it * 4 + wid;  // 32 segs x 1024 B
      gload_lds16(&Spg[seg * 512 + lane * 8], &attb[seg * 512]);
    }
  }
#pragma unroll
  for (int it = 0; it < 4; ++it) {
    int flat = tid + it * 256; int v = flat >> 4, sb = flat & 15;
    *(us8*)&VT[v][sb * 8] = *(const us8*)&VTg[((size_t)bh * 64 + v) * T_SEQ + c * CH + sb * 8];
  }
  mksh[tid] = Mkp[((size_t)bh * NCHUNK + c) * 256 + tid];
  __syncthreads();  // drains vmcnt (Sp staged) + lgkm

  const int tb = wid * 32;
  const f32x4 zero4 = {0.f, 0.f, 0.f, 0.f};

  f32x4 o[2][4];
#pragma unroll
  for (int mt = 0; mt < 2; ++mt)
#pragma unroll
    for (int nt = 0; nt < 4; ++nt) o[mt][nt] = zero4;

  // --- inter phase (K=256 over qf; B = staged Sp in LDS, XOR-swizzled) ---
  {
    bf16x8 xlo0 = *(const bf16x8*)&XQb[tb + ln][0];
    bf16x8 xhi0 = *(const bf16x8*)&XQb[tb + ln][8];
    bf16x8 xlo1 = *(const bf16x8*)&XQb[tb + 16 + ln][0];
    bf16x8 xhi1 = *(const bf16x8*)&XQb[tb + 16 + ln][8];
#pragma unroll
    for (int kt = 0; kt < 8; ++kt) {
      int i = kt * 2 + (lg >> 1);
      float xqi0 = b2f(XQb[tb + ln][i]) * 0.0625f;
      float xqi1 = b2f(XQb[tb + 16 + ln][i]) * 0.0625f;
      bf16x8 sel0 = (lg & 1) ? xhi0 : xlo0;
      bf16x8 sel1 = (lg & 1) ? xhi1 : xlo1;
      bf16x8 qa0, qa1;
#pragma unroll
      for (int jj = 0; jj < 8; ++jj) {
        qa0[jj] = (short)f2b(xqi0 * b2f((unsigned short)sel0[jj]));
        qa1[jj] = (short)f2b(xqi1 * b2f((unsigned short)sel1[jj]));
      }
      int r0 = kt * 32 + lg * 8;
#pragma unroll
      for (int nt = 0; nt < 4; ++nt) {
        int n = nt * 16 + ln;
        bf16x8 bp = *(const bf16x8*)&attb[n * 256 + (r0 ^ ((ln & 7) << 3))];
        o[0][nt] = __builtin_amdgcn_mfma_f32_16x16x32_bf16(qa0, bp, o[0][nt], 0, 0, 0);
        o[1][nt] = __builtin_amdgcn_mfma_f32_16x16x32_bf16(qa1, bp, o[1][nt], 0, 0, 0);
      }
    }
  }

  // --- z_inter (f32, lane-distributed; Mk symmetric) ---
  float zi2[2][4];
#pragma unroll
  for (int mt = 0; mt < 2; ++mt)
#pragma unroll
    for (int j = 0; j < 4; ++j) {
      int t = tb + mt * 16 + lg * 4 + j;
      float xqi = b2f(XQb[t][ln]);
      float p = 0.f;
#pragma unroll
      for (int jm = 0; jm < 16; ++jm) p += b2f(XQb[t][jm]) * mksh[jm * 16 + ln];
      p *= xqi;
      p += __shfl_xor(p, 1, 64);
      p += __shfl_xor(p, 2, 64);
      p += __shfl_xor(p, 4, 64);
      p += __shfl_xor(p, 8, 64);
      zi2[mt][j] = p * 0.0625f;
    }

  __syncthreads();  // all waves done reading Sp before att overwrites attb

  // --- att phase (K=16 padded to 32) ---
  bf16x8 aq0 = *(const bf16x8*)&XQb[tb + ln][lg * 8];
  bf16x8 aq1 = *(const bf16x8*)&XQb[tb + 16 + ln][lg * 8];
  float zin[2][4];
#pragma unroll
  for (int mt = 0; mt < 2; ++mt)
#pragma unroll
    for (int j = 0; j < 4; ++j) zin[mt][j] = 0.f;

#pragma unroll
  for (int nt = 0; nt < 8; ++nt) {
    bf16x8 bk = *(const bf16x8*)&XKb[nt * 16 + ln][lg * 8];
    f32x4 c0 = __builtin_amdgcn_mfma_f32_16x16x32_bf16(aq0, bk, zero4, 0, 0, 0);
    f32x4 c1 = __builtin_amdgcn_mfma_f32_16x16x32_bf16(aq1, bk, zero4, 0, 0, 0);
    int s = nt * 16 + ln;
#pragma unroll
    for (int j = 0; j < 4; ++j) {
      int t0 = tb + lg * 4 + j;
      float d0 = c0[j];
      float a0 = (s <= t0) ? d0 * d0 * 0.0625f : 0.f;
      zin[0][j] += a0;
      attb[t0 * 128 + (s ^ ((t0 & 7) << 3))] = f2b(a0);
      int t1 = t0 + 16;
      float d1 = c1[j];
      float a1 = (s <= t1) ? d1 * d1 * 0.0625f : 0.f;
      zin[1][j] += a1;
      attb[t1 * 128 + (s ^ ((t1 & 7) << 3))] = f2b(a1);
    }
  }
#pragma unroll
  for (int mt = 0; mt < 2; ++mt)
#pragma unroll
    for (int j = 0; j < 4; ++j) {
      float zz = zin[mt][j];
      zz += __shfl_xor(zz, 1, 64);
      zz += __shfl_xor(zz, 2, 64);
      zz += __shfl_xor(zz, 4, 64);
      zz += __shfl_xor(zz, 8, 64);
      zin[mt][j] = zz;
    }

  // --- PV intra (K=128 over att; wave reads only its own rows) ---
#pragma unroll
  for (int kt = 0; kt < 4; ++kt) {
    int s0 = kt * 32 + lg * 8;
    bf16x8 a0 = *(const bf16x8*)&attb[(tb + ln) * 128 + (s0 ^ ((ln & 7) << 3))];
    bf16x8 a1 = *(const bf16x8*)&attb[(tb + 16 + ln) * 128 + (s0 ^ ((ln & 7) << 3))];
#pragma unroll
    for (int nt = 0; nt < 4; ++nt) {
      bf16x8 bv = *(const bf16x8*)&VT[nt * 16 + ln][s0];
      o[0][nt] = __builtin_amdgcn_mfma_f32_16x16x32_bf16(a0, bv, o[0][nt], 0, 0, 0);
      o[1][nt] = __builtin_amdgcn_mfma_f32_16x16x32_bf16(a1, bv, o[1][nt], 0, 0, 0);
    }
  }

  unsigned short* ob = OAB + ((size_t)(b * T_SEQ + c * CH)) * 1024 + h * 64;
#pragma unroll
  for (int mt = 0; mt < 2; ++mt)
#pragma unroll
    for (int j = 0; j < 4; ++j) {
      int t = tb + mt * 16 + lg * 4 + j;
      float inv = 1.0f / (zin[mt][j] + zi2[mt][j] + 1e-10f);
#pragma unroll
      for (int nt = 0; nt < 4; ++nt)
        ob[(size_t)t * 1024 + nt * 16 + ln] = f2b(o[mt][nt][j] * inv);
    }
}

// ---------------------------------------------------------------------------
extern "C" void kernel_launch(void* const* d_in, const int* in_sizes, int n_in,
                              void* d_out, int out_size, void* d_ws, size_t ws_size,
                              hipStream_t stream) {
  const float* hs    = (const float*)d_in[0];
  const float* Wq    = (const float*)d_in[1];
  const float* Wk    = (const float*)d_in[2];
  const float* Wv    = (const float*)d_in[3];
  const float* Wo    = (const float*)d_in[4];
  const float* gamma = (const float*)d_in[5];
  const float* beta  = (const float*)d_in[6];
  float* out = (float*)d_out;
  float* ws  = (float*)d_ws;

  float* QK = ws + QK_OFF;
  unsigned short* VTg   = (unsigned short*)(ws + VT_OFF);
  unsigned short* Sraw  = (unsigned short*)(ws + SRAW_OFF);
  unsigned short* Spre  = (unsigned short*)(ws + SPRE_OFF);
  float* Mk = ws + MK_OFF;
  unsigned short* OAB   = (unsigned short*)(ws + OAB_OFF);
  unsigned short* WQKVB = (unsigned short*)(ws + WQKV_OFF);
  unsigned short* WOB   = (unsigned short*)(ws + WO_OFF);
  unsigned short* HSB   = (unsigned short*)(ws + HSB_OFF);

  dim3 blk(256);
  conv_all<<<5376, blk, 0, stream>>>(hs, Wq, Wk, Wv, Wo, HSB, WQKVB, WOB);
  proj_gemm<<<768, blk, 0, stream>>>(HSB, WQKVB, QK, VTg);
  k_states<<<dim3(NCHUNK, NBH), blk, 0, stream>>>(QK, VTg, gamma, beta, Sraw, Mk);
  k_prefix<<<dim3(9, NBH), blk, 0, stream>>>(Sraw, Spre, Mk);
  k_attn_out<<<dim3(NCHUNK, NBH), blk, 0, stream>>>(QK, VTg, gamma, beta, Spre, Mk, OAB);
  out_gemm<<<512, blk, 0, stream>>>(OAB, WOB, out);
}

// Round 11
// 121.960 us; speedup vs baseline: 1.1818x; 1.0275x over previous
//
#include <hip/hip_runtime.h>

#define T_SEQ 2048
#define BATCH 4
#define NH 16
#define FDIM 16
#define HDIM 64
#define HIDDEN 1024
#define TOK (BATCH * T_SEQ)      // 8192
#define CH 128
#define NCHUNK (T_SEQ / CH)      // 16
#define NBH (BATCH * NH)         // 64

// workspace offsets (float32 units)
#define QK_OFF   0u              // bf16 [TOK, 512]  (Q cols 0..255, K cols 256..511)
#define VT_OFF   4194304u        // bf16 [NBH][64 v][2048 t]
#define SRAW_OFF 8388608u        // bf16 [NBH][NCHUNK][64 n][256 r] (linear)
#define SPRE_OFF 16777216u       // bf16 same extent, XOR-swizzled (r ^= (n&7)<<3)
#define MK_OFF   25165824u       // f32 [NBH][NCHUNK][256] (exclusive prefix)
#define OAB_OFF  25427968u       // bf16 [TOK,1024]
#define WQKV_OFF 29622272u       // bf16 [1536,1024] (Wq 0-255, Wk 256-511, Wv 512-1535)
#define WO_OFF   30408704u       // bf16 [1024,1024]
#define HSB_OFF  30932992u       // bf16 [TOK,1024]

typedef float f32x4 __attribute__((ext_vector_type(4)));
typedef short bf16x8 __attribute__((ext_vector_type(8)));
typedef unsigned short us8 __attribute__((ext_vector_type(8)));
typedef unsigned short us4 __attribute__((ext_vector_type(4)));
typedef unsigned int u32;

__device__ __forceinline__ unsigned short f2b(float f) {
  union { float f; unsigned u; } v; v.f = f;
  unsigned r = (v.u + 0x7FFFu + ((v.u >> 16) & 1u)) >> 16;
  return (unsigned short)r;
}
__device__ __forceinline__ float b2f(unsigned short h) {
  union { unsigned u; float f; } v; v.u = ((unsigned)h) << 16; return v.f;
}

__device__ __forceinline__ void gload_lds16(const void* g, void* l) {
  __builtin_amdgcn_global_load_lds(
      (const __attribute__((address_space(1))) u32*)g,
      (__attribute__((address_space(3))) u32*)l, 16, 0, 0);
}

// ---------------------------------------------------------------------------
// One convert kernel: hs -> HSB, Wq|Wk|Wv -> WQKVB, Wo -> WOB. 8 elts/thread.
// ---------------------------------------------------------------------------
__global__ __launch_bounds__(256) void conv_all(const float* __restrict__ hs,
                                                const float* __restrict__ Wq,
                                                const float* __restrict__ Wk,
                                                const float* __restrict__ Wv,
                                                const float* __restrict__ Wo,
                                                unsigned short* __restrict__ HSB,
                                                unsigned short* __restrict__ WQKVB,
                                                unsigned short* __restrict__ WOB) {
  int i = blockIdx.x * 256 + threadIdx.x;
  const float* src;
  unsigned short* dst;
  if (i < 1048576) {
    int f = i * 8; src = hs + f; dst = HSB + f;
  } else if (i < 1245184) {
    int f = (i - 1048576) * 8;
    if (f < 262144)      src = Wq + f;
    else if (f < 524288) src = Wk + (f - 262144);
    else                 src = Wv + (f - 524288);
    dst = WQKVB + f;
  } else {
    int f = (i - 1245184) * 8;
    src = Wo + f; dst = WOB + f;
  }
  float4 v0 = *(const float4*)src, v1 = *(const float4*)(src + 4);
  us8 o;
  o[0] = f2b(v0.x); o[1] = f2b(v0.y); o[2] = f2b(v0.z); o[3] = f2b(v0.w);
  o[4] = f2b(v1.x); o[5] = f2b(v1.y); o[6] = f2b(v1.z); o[7] = f2b(v1.w);
  *(us8*)dst = o;
}

// ---------------------------------------------------------------------------
// GEMM core: BM=BN=128, BK=64, 256 thr (4 waves 2x2). 2-deep LDS (64 KiB ->
// 2 blocks/CU). Counted vmcnt(8), T2 swizzle both-sides, T5 setprio.
// ---------------------------------------------------------------------------
#define LDSA(p) (lds + (p) * 8192)
#define LDSB(p) (lds + 16384 + (p) * 8192)

__device__ __forceinline__ void stage8(const unsigned short* __restrict__ A,
                                       const unsigned short* __restrict__ B,
                                       int m0, int n0, int kt,
                                       unsigned short* lA, unsigned short* lB,
                                       int w, int lrow, int kswz) {
  const int kc = kt * 64 + kswz;
#pragma unroll
  for (int i = 0; i < 4; ++i) {
    int r = w * 32 + i * 8;
    gload_lds16(&A[(size_t)(m0 + r + lrow) * HIDDEN + kc], &lA[r * 64]);
  }
#pragma unroll
  for (int i = 0; i < 4; ++i) {
    int r = w * 32 + i * 8;
    gload_lds16(&B[(size_t)(n0 + r + lrow) * HIDDEN + kc], &lB[r * 64]);
  }
}

#define RD_A(fm, kk) (*(const bf16x8*)&cA[(wm * 64 + (fm) * 16 + ln) * 64 + (((kk) * 32 + lg * 8) ^ swz)])
#define RD_B(fn, kk) (*(const bf16x8*)&cB[(wn * 64 + (fn) * 16 + ln) * 64 + (((kk) * 32 + lg * 8) ^ swz)])

#define GEMM_PIPELINE(Aptr, Bptr)                                              \
  const int tid = threadIdx.x;                                                 \
  const int lane = tid & 63, w = tid >> 6;                                     \
  const int wm = w >> 1, wn = w & 1;                                           \
  const int ln = lane & 15, lg = lane >> 4;                                    \
  const int lrow = lane >> 3;                                                  \
  const int kswz = (((lane & 7) ^ ((lane >> 3) & 7)) * 8);                     \
  const int swz = (ln & 7) << 3;                                               \
  f32x4 acc[4][4];                                                             \
  _Pragma("unroll") for (int m = 0; m < 4; ++m)                                \
    _Pragma("unroll") for (int n = 0; n < 4; ++n)                              \
      acc[m][n] = (f32x4){0.f, 0.f, 0.f, 0.f};                                 \
  stage8(Aptr, Bptr, m0, n0, 0, LDSA(0), LDSB(0), w, lrow, kswz);              \
  stage8(Aptr, Bptr, m0, n0, 1, LDSA(1), LDSB(1), w, lrow, kswz);              \
  asm volatile("s_waitcnt vmcnt(8)" ::: "memory");                             \
  __builtin_amdgcn_s_barrier();                                                \
  _Pragma("unroll 1") for (int t = 0; t < 16; ++t) {                           \
    const unsigned short* cA = LDSA(t & 1);                                    \
    const unsigned short* cB = LDSB(t & 1);                                    \
    bf16x8 af[4][2], bfr[4][2];                                                \
    _Pragma("unroll") for (int f = 0; f < 4; ++f) {                            \
      af[f][0] = RD_A(f, 0); af[f][1] = RD_A(f, 1);                            \
      bfr[f][0] = RD_B(f, 0); bfr[f][1] = RD_B(f, 1);                          \
    }                                                                          \
    asm volatile("s_waitcnt lgkmcnt(0)" ::: "memory");                         \
    __builtin_amdgcn_sched_barrier(0);                                         \
    __builtin_amdgcn_s_barrier();                                              \
    if (t <= 13)                                                               \
      stage8(Aptr, Bptr, m0, n0, t + 2, LDSA(t & 1), LDSB(t & 1), w, lrow, kswz); \
    __builtin_amdgcn_s_setprio(1);                                             \
    _Pragma("unroll") for (int kk = 0; kk < 2; ++kk)                           \
      _Pragma("unroll") for (int fm = 0; fm < 4; ++fm)                         \
        _Pragma("unroll") for (int fn = 0; fn < 4; ++fn)                       \
          acc[fm][fn] = __builtin_amdgcn_mfma_f32_16x16x32_bf16(               \
              af[fm][kk], bfr[fn][kk], acc[fm][fn], 0, 0, 0);                  \
    __builtin_amdgcn_s_setprio(0);                                             \
    if (t <= 13) { asm volatile("s_waitcnt vmcnt(8)" ::: "memory"); }          \
    else if (t == 14) { asm volatile("s_waitcnt vmcnt(0)" ::: "memory"); }     \
    __builtin_amdgcn_s_barrier();                                              \
  }

// ---------------------------------------------------------------------------
// Fused QKV projection: A=HSB [8192,1024], W=WQKVB [1536,1024].
// by 0-3 -> QKB bf16 [8192,512] (LDS-staged coalesced us8 stores);
// by 4-11 -> V transposed to VTg[bh][v][t].
// Grid 768 = 64 bx * 12 by, bijective XCD swizzle, N-fastest within XCD.
// ---------------------------------------------------------------------------
__global__ __launch_bounds__(256) void proj_gemm(const unsigned short* __restrict__ A,
                                                 const unsigned short* __restrict__ Wb,
                                                 unsigned short* __restrict__ QKB,
                                                 unsigned short* __restrict__ VTg) {
  __shared__ unsigned short lds[32768];  // 64 KiB
  const int bid = blockIdx.x;
  const int logical = (bid & 7) * 96 + (bid >> 3);  // 768 % 8 == 0
  const int bx = logical / 12, by = logical % 12;
  const int m0 = bx * 128, n0 = by * 128;

  GEMM_PIPELINE(A, Wb)

  unsigned short (*ct)[136] = (unsigned short(*)[136])lds;
  if (by < 4) {
    // QK path: stage [row][col] bf16 tile, then coalesced us8 row-major stores
#pragma unroll
    for (int fm = 0; fm < 4; ++fm)
#pragma unroll
      for (int fn = 0; fn < 4; ++fn) {
        int cl = wn * 64 + fn * 16 + ln;        // local col 0..127
        int r0 = wm * 64 + fm * 16 + lg * 4;    // local row
#pragma unroll
        for (int j = 0; j < 4; ++j) ct[r0 + j][cl] = f2b(acc[fm][fn][j]);
      }
    __builtin_amdgcn_s_barrier();
    asm volatile("" ::: "memory");
#pragma unroll
    for (int it = 0; it < 8; ++it) {
      int sid = it * 256 + tid, row = sid >> 4, tc = sid & 15;
      us8 val = *(const us8*)&ct[row][tc * 8];
      *(us8*)&QKB[(size_t)(m0 + row) * 512 + n0 + tc * 8] = val;
    }
  } else {
    // V path: stage transposed tile in LDS, then coalesced 16B stores along t
#pragma unroll
    for (int fm = 0; fm < 4; ++fm)
#pragma unroll
      for (int fn = 0; fn < 4; ++fn) {
        int cl = wn * 64 + fn * 16 + ln;        // local v col 0..127
        int r0 = wm * 64 + fm * 16 + lg * 4;    // local t row 0..127
        us4 p;
#pragma unroll
        for (int j = 0; j < 4; ++j) p[j] = f2b(acc[fm][fn][j]);
        *(us4*)&ct[cl][r0] = p;
      }
    __builtin_amdgcn_s_barrier();
    asm volatile("" ::: "memory");
    const int vbase = n0 - 512;
    const int b = m0 >> 11, t0 = m0 & 2047;
#pragma unroll
    for (int it = 0; it < 8; ++it) {
      int sid = it * 256 + tid, vl = sid >> 4, tc = sid & 15;
      int vg = vbase + vl, h = vg >> 6, vd = vg & 63;
      us8 val = *(const us8*)&ct[vl][tc * 8];
      *(us8*)&VTg[(((size_t)(b * 16 + h) * 64 + vd) << 11) + t0 + tc * 8] = val;
    }
  }
}

// ---------------------------------------------------------------------------
// Output GEMM: C[8192,1024] f32. Grid 512 = 64 bx * 8 by, XCD-swizzled.
// ---------------------------------------------------------------------------
__global__ __launch_bounds__(256) void out_gemm(const unsigned short* __restrict__ A,
                                                const unsigned short* __restrict__ W,
                                                float* __restrict__ C) {
  __shared__ unsigned short lds[32768];  // 64 KiB
  const int bid = blockIdx.x;
  const int logical = (bid & 7) * 64 + (bid >> 3);  // 512 % 8 == 0
  const int bx = logical >> 3, by = logical & 7;
  const int m0 = bx * 128, n0 = by * 128;

  GEMM_PIPELINE(A, W)

#pragma unroll
  for (int fm = 0; fm < 4; ++fm)
#pragma unroll
    for (int fn = 0; fn < 4; ++fn) {
      int col = n0 + wn * 64 + fn * 16 + ln;
      int row0 = m0 + wm * 64 + fm * 16 + lg * 4;
#pragma unroll
      for (int j = 0; j < 4; ++j)
        C[(size_t)(row0 + j) * 1024 + col] = acc[fm][fn][j];
    }
}

// ---------------------------------------------------------------------------
// LayerNorm over 16 features, bf16 input
// ---------------------------------------------------------------------------
__device__ __forceinline__ void ln16b(const unsigned short* __restrict__ src,
                                      const float* __restrict__ gamma,
                                      const float* __restrict__ beta,
                                      float* dst) {
  us8 lo = *(const us8*)src;
  us8 hi = *(const us8*)(src + 8);
  float x[16];
#pragma unroll
  for (int q = 0; q < 8; ++q) { x[q] = b2f(lo[q]); x[8 + q] = b2f(hi[q]); }
  float mu = 0.f;
#pragma unroll
  for (int f = 0; f < 16; ++f) mu += x[f];
  mu *= 0.0625f;
  float var = 0.f;
#pragma unroll
  for (int f = 0; f < 16; ++f) { float d = x[f] - mu; var += d * d; }
  var *= 0.0625f;
  const float rs = rsqrtf(var + 1e-5f);
#pragma unroll
  for (int f = 0; f < 16; ++f) dst[f] = (x[f] - mu) * rs * gamma[f] + beta[f];
}

// ---------------------------------------------------------------------------
// Phase 1 (MFMA): S_raw_T[n][r] = sum_s kf[s][r] * V[s][n].
// Mk gram via MFMA on wave 0 (XK^T XK, K=128; symmetric so layout-safe).
// ---------------------------------------------------------------------------
__global__ __launch_bounds__(256) void k_states(const unsigned short* __restrict__ QKB,
                                                const unsigned short* __restrict__ VTg,
                                                const float* __restrict__ gamma,
                                                const float* __restrict__ beta,
                                                unsigned short* __restrict__ Sraw,
                                                float* __restrict__ Mk) {
  const int c = blockIdx.x, bh = blockIdx.y;
  const int b = bh >> 4, h = bh & 15;
  __shared__ float XKT[16][140];
  __shared__ unsigned short VT[64][152];
  const int tid = threadIdx.x;
  const int lane = tid & 63, wid = tid >> 6;
  const int ln = lane & 15, lg = lane >> 4;

  if (tid < 128) {
    float xr[16];
    ln16b(QKB + (size_t)(b * T_SEQ + c * CH + tid) * 512 + 256 + h * FDIM, gamma, beta, xr);
#pragma unroll
    for (int f = 0; f < 16; ++f) XKT[f][tid] = xr[f];
  }
#pragma unroll
  for (int it = 0; it < 4; ++it) {
    int flat = tid + it * 256; int v = flat >> 4, sb = flat & 15;
    *(us8*)&VT[v][sb * 8] = *(const us8*)&VTg[((size_t)bh * 64 + v) * T_SEQ + c * CH + sb * 8];
  }
  __syncthreads();

  // Gram via MFMA (wave 0 only): Mk[i][j] = sum_s XK[i][s] XK[j][s]
  if (wid == 0) {
    f32x4 g = (f32x4){0.f, 0.f, 0.f, 0.f};
#pragma unroll
    for (int kt = 0; kt < 4; ++kt) {
      const int s0 = kt * 32 + lg * 8;
      float4 xa = *(const float4*)&XKT[ln][s0];
      float4 xb = *(const float4*)&XKT[ln][s0 + 4];
      bf16x8 ga;
      ga[0] = (short)f2b(xa.x); ga[1] = (short)f2b(xa.y);
      ga[2] = (short)f2b(xa.z); ga[3] = (short)f2b(xa.w);
      ga[4] = (short)f2b(xb.x); ga[5] = (short)f2b(xb.y);
      ga[6] = (short)f2b(xb.z); ga[7] = (short)f2b(xb.w);
      g = __builtin_amdgcn_mfma_f32_16x16x32_bf16(ga, ga, g, 0, 0, 0);
    }
    float* mkp = Mk + ((size_t)bh * NCHUNK + c) * 256;
#pragma unroll
    for (int j = 0; j < 4; ++j) mkp[(lg * 4 + j) * 16 + ln] = g[j];
  }

  f32x4 acc[4][4];
#pragma unroll
  for (int m = 0; m < 4; ++m)
#pragma unroll
    for (int n = 0; n < 4; ++n) acc[m][n] = (f32x4){0.f, 0.f, 0.f, 0.f};

#pragma unroll
  for (int kt = 0; kt < 4; ++kt) {
    const int s0 = kt * 32 + lg * 8;
    bf16x8 bfr[4];
#pragma unroll
    for (int nt = 0; nt < 4; ++nt) bfr[nt] = *(const bf16x8*)&VT[nt * 16 + ln][s0];
#pragma unroll
    for (int mi = 0; mi < 4; ++mi) {
      const int iidx = wid * 4 + mi;
      float4 xi0 = *(const float4*)&XKT[iidx][s0];
      float4 xi1 = *(const float4*)&XKT[iidx][s0 + 4];
      float4 xj0 = *(const float4*)&XKT[ln][s0];
      float4 xj1 = *(const float4*)&XKT[ln][s0 + 4];
      bf16x8 afr;
      afr[0] = (short)f2b(xi0.x * xj0.x); afr[1] = (short)f2b(xi0.y * xj0.y);
      afr[2] = (short)f2b(xi0.z * xj0.z); afr[3] = (short)f2b(xi0.w * xj0.w);
      afr[4] = (short)f2b(xi1.x * xj1.x); afr[5] = (short)f2b(xi1.y * xj1.y);
      afr[6] = (short)f2b(xi1.z * xj1.z); afr[7] = (short)f2b(xi1.w * xj1.w);
#pragma unroll
      for (int nt = 0; nt < 4; ++nt)
        acc[mi][nt] = __builtin_amdgcn_mfma_f32_16x16x32_bf16(afr, bfr[nt], acc[mi][nt], 0, 0, 0);
    }
  }

  unsigned short* Sp = Sraw + ((size_t)bh * NCHUNK + c) * (64 * 256);
#pragma unroll
  for (int mi = 0; mi < 4; ++mi) {
    int r0 = (wid * 4 + mi) * 16 + lg * 4;
#pragma unroll
    for (int nt = 0; nt < 4; ++nt) {
      int n = nt * 16 + ln;
      us4 pk;
#pragma unroll
      for (int j = 0; j < 4; ++j) pk[j] = f2b(acc[mi][nt][j]);
      *(us4*)&Sp[(size_t)n * 256 + r0] = pk;
    }
  }
}

// ---------------------------------------------------------------------------
// Phase 2 merged: blockIdx.x<8 -> S prefix (writes Spre XOR-SWIZZLED:
// elem (n,r) stored at n*256 + (r ^ ((n&7)<<3))); ==8 -> Mk prefix.
// 1-deep software pipeline on the chunk loop.
// ---------------------------------------------------------------------------
__global__ __launch_bounds__(256) void k_prefix(const unsigned short* __restrict__ Sraw,
                                                unsigned short* __restrict__ Spre,
                                                float* __restrict__ Mk) {
  const int bh = blockIdx.y;
  if (blockIdx.x < 8) {
    const int e8 = blockIdx.x * 256 + threadIdx.x;  // < 2048 (8-elem units)
    const int n = (e8 * 8) >> 8, r = (e8 * 8) & 255;
    const int rsw = r ^ ((n & 7) << 3);             // aligned-8 XOR, stays in [0,256)
    size_t rbase = (size_t)bh * NCHUNK * 16384 + (size_t)e8 * 8;
    size_t wbase = (size_t)bh * NCHUNK * 16384 + (size_t)n * 256 + rsw;
    float run[8] = {0.f, 0.f, 0.f, 0.f, 0.f, 0.f, 0.f, 0.f};
    us8 v = *(const us8*)&Sraw[rbase];
    for (int cc = 0; cc < NCHUNK; ++cc) {
      us8 vn;
      if (cc < NCHUNK - 1) vn = *(const us8*)&Sraw[rbase + (size_t)(cc + 1) * 16384];
      us8 wv;
#pragma unroll
      for (int q = 0; q < 8; ++q) wv[q] = f2b(run[q]);
      *(us8*)&Spre[wbase + (size_t)cc * 16384] = wv;
#pragma unroll
      for (int q = 0; q < 8; ++q) run[q] += b2f(v[q]);
      v = vn;
    }
  } else {
    const int e = threadIdx.x;
    size_t base = (size_t)bh * NCHUNK * 256 + e;
    float run = 0.f;
    for (int c = 0; c < NCHUNK; ++c) {
      float v = Mk[base + (size_t)c * 256];
      Mk[base + (size_t)c * 256] = run;
      run += v;
    }
  }
}

// ---------------------------------------------------------------------------
// Phase 3 (MFMA): inter (staged swizzled Sp in LDS) FIRST, then att, then PV.
// ---------------------------------------------------------------------------
__global__ __launch_bounds__(256) void k_attn_out(const unsigned short* __restrict__ QKB,
                                                  const unsigned short* __restrict__ VTg,
                                                  const float* __restrict__ gamma,
                                                  const float* __restrict__ beta,
                                                  const unsigned short* __restrict__ Spre,
                                                  const float* __restrict__ Mkp,
                                                  unsigned short* __restrict__ OAB) {
  const int c = blockIdx.x, bh = blockIdx.y;
  const int b = bh >> 4, h = bh & 15;
  __shared__ unsigned short XQb[128][40];
  __shared__ unsigned short XKb[128][40];
  __shared__ unsigned short attb[128 * 128];  // holds Sp (swizzled) then att
  __shared__ unsigned short VT[64][152];
  __shared__ float mksh[256];
  const int tid = threadIdx.x;
  const int lane = tid & 63, wid = tid >> 6;
  const int ln = lane & 15, lg = lane >> 4;

  {
    int r = tid & 127;
    const unsigned short* src = QKB + (size_t)(b * T_SEQ + c * CH + r) * 512 + (tid < 128 ? 0 : 256) + h * FDIM;
    unsigned short* dst = (tid < 128) ? &XQb[r][0] : &XKb[r][0];
    float xr[16];
    ln16b(src, gamma, beta, xr);
    us8 lo, hi, z8;
#pragma unroll
    for (int q = 0; q < 8; ++q) { lo[q] = f2b(xr[q]); hi[q] = f2b(xr[8 + q]); z8[q] = 0; }
    *(us8*)&dst[0] = lo; *(us8*)&dst[8] = hi;
    *(us8*)&dst[16] = z8; *(us8*)&dst[24] = z8;
  }
  // stage swizzled Sp (32 KB) into attb via coalesced global_load_lds
  {
    const unsigned short* Spg = Spre + ((size_t)bh * NCHUNK + c) * (64 * 256);
#pragma unroll
    for (int it = 0; it < 8; ++it) {
      int seg = it * 4 + wid;  // 32 segs x 1024 B
      gload_lds16(&Spg[seg * 512 + lane * 8], &attb[seg * 512]);
    }
  }
#pragma unroll
  for (int it = 0; it < 4; ++it) {
    int flat = tid + it * 256; int v = flat >> 4, sb = flat & 15;
    *(us8*)&VT[v][sb * 8] = *(const us8*)&VTg[((size_t)bh * 64 + v) * T_SEQ + c * CH + sb * 8];
  }
  mksh[tid] = Mkp[((size_t)bh * NCHUNK + c) * 256 + tid];
  __syncthreads();  // drains vmcnt (Sp staged) + lgkm

  const int tb = wid * 32;
  const f32x4 zero4 = {0.f, 0.f, 0.f, 0.f};

  f32x4 o[2][4];
#pragma unroll
  for (int mt = 0; mt < 2; ++mt)
#pragma unroll
    for (int nt = 0; nt < 4; ++nt) o[mt][nt] = zero4;

  // --- inter phase (K=256 over qf; B = staged Sp in LDS, XOR-swizzled) ---
  {
    bf16x8 xlo0 = *(const bf16x8*)&XQb[tb + ln][0];
    bf16x8 xhi0 = *(const bf16x8*)&XQb[tb + ln][8];
    bf16x8 xlo1 = *(const bf16x8*)&XQb[tb + 16 + ln][0];
    bf16x8 xhi1 = *(const bf16x8*)&XQb[tb + 16 + ln][8];
#pragma unroll
    for (int kt = 0; kt < 8; ++kt) {
      int i = kt * 2 + (lg >> 1);
      float xqi0 = b2f(XQb[tb + ln][i]) * 0.0625f;
      float xqi1 = b2f(XQb[tb + 16 + ln][i]) * 0.0625f;
      bf16x8 sel0 = (lg & 1) ? xhi0 : xlo0;
      bf16x8 sel1 = (lg & 1) ? xhi1 : xlo1;
      bf16x8 qa0, qa1;
#pragma unroll
      for (int jj = 0; jj < 8; ++jj) {
        qa0[jj] = (short)f2b(xqi0 * b2f((unsigned short)sel0[jj]));
        qa1[jj] = (short)f2b(xqi1 * b2f((unsigned short)sel1[jj]));
      }
      int r0 = kt * 32 + lg * 8;
#pragma unroll
      for (int nt = 0; nt < 4; ++nt) {
        int n = nt * 16 + ln;
        bf16x8 bp = *(const bf16x8*)&attb[n * 256 + (r0 ^ ((ln & 7) << 3))];
        o[0][nt] = __builtin_amdgcn_mfma_f32_16x16x32_bf16(qa0, bp, o[0][nt], 0, 0, 0);
        o[1][nt] = __builtin_amdgcn_mfma_f32_16x16x32_bf16(qa1, bp, o[1][nt], 0, 0, 0);
      }
    }
  }

  // --- z_inter (f32, lane-distributed; Mk symmetric) ---
  float zi2[2][4];
#pragma unroll
  for (int mt = 0; mt < 2; ++mt)
#pragma unroll
    for (int j = 0; j < 4; ++j) {
      int t = tb + mt * 16 + lg * 4 + j;
      float xqi = b2f(XQb[t][ln]);
      float p = 0.f;
#pragma unroll
      for (int jm = 0; jm < 16; ++jm) p += b2f(XQb[t][jm]) * mksh[jm * 16 + ln];
      p *= xqi;
      p += __shfl_xor(p, 1, 64);
      p += __shfl_xor(p, 2, 64);
      p += __shfl_xor(p, 4, 64);
      p += __shfl_xor(p, 8, 64);
      zi2[mt][j] = p * 0.0625f;
    }

  __syncthreads();  // all waves done reading Sp before att overwrites attb

  // --- att phase (K=16 padded to 32) ---
  bf16x8 aq0 = *(const bf16x8*)&XQb[tb + ln][lg * 8];
  bf16x8 aq1 = *(const bf16x8*)&XQb[tb + 16 + ln][lg * 8];
  float zin[2][4];
#pragma unroll
  for (int mt = 0; mt < 2; ++mt)
#pragma unroll
    for (int j = 0; j < 4; ++j) zin[mt][j] = 0.f;

#pragma unroll
  for (int nt = 0; nt < 8; ++nt) {
    bf16x8 bk = *(const bf16x8*)&XKb[nt * 16 + ln][lg * 8];
    f32x4 c0 = __builtin_amdgcn_mfma_f32_16x16x32_bf16(aq0, bk, zero4, 0, 0, 0);
    f32x4 c1 = __builtin_amdgcn_mfma_f32_16x16x32_bf16(aq1, bk, zero4, 0, 0, 0);
    int s = nt * 16 + ln;
#pragma unroll
    for (int j = 0; j < 4; ++j) {
      int t0 = tb + lg * 4 + j;
      float d0 = c0[j];
      float a0 = (s <= t0) ? d0 * d0 * 0.0625f : 0.f;
      zin[0][j] += a0;
      attb[t0 * 128 + (s ^ ((t0 & 7) << 3))] = f2b(a0);
      int t1 = t0 + 16;
      float d1 = c1[j];
      float a1 = (s <= t1) ? d1 * d1 * 0.0625f : 0.f;
      zin[1][j] += a1;
      attb[t1 * 128 + (s ^ ((t1 & 7) << 3))] = f2b(a1);
    }
  }
#pragma unroll
  for (int mt = 0; mt < 2; ++mt)
#pragma unroll
    for (int j = 0; j < 4; ++j) {
      float zz = zin[mt][j];
      zz += __shfl_xor(zz, 1, 64);
      zz += __shfl_xor(zz, 2, 64);
      zz += __shfl_xor(zz, 4, 64);
      zz += __shfl_xor(zz, 8, 64);
      zin[mt][j] = zz;
    }

  // --- PV intra (K=128 over att; wave reads only its own rows) ---
#pragma unroll
  for (int kt = 0; kt < 4; ++kt) {
    int s0 = kt * 32 + lg * 8;
    bf16x8 a0 = *(const bf16x8*)&attb[(tb + ln) * 128 + (s0 ^ ((ln & 7) << 3))];
    bf16x8 a1 = *(const bf16x8*)&attb[(tb + 16 + ln) * 128 + (s0 ^ ((ln & 7) << 3))];
#pragma unroll
    for (int nt = 0; nt < 4; ++nt) {
      bf16x8 bv = *(const bf16x8*)&VT[nt * 16 + ln][s0];
      o[0][nt] = __builtin_amdgcn_mfma_f32_16x16x32_bf16(a0, bv, o[0][nt], 0, 0, 0);
      o[1][nt] = __builtin_amdgcn_mfma_f32_16x16x32_bf16(a1, bv, o[1][nt], 0, 0, 0);
    }
  }

  unsigned short* ob = OAB + ((size_t)(b * T_SEQ + c * CH)) * 1024 + h * 64;
#pragma unroll
  for (int mt = 0; mt < 2; ++mt)
#pragma unroll
    for (int j = 0; j < 4; ++j) {
      int t = tb + mt * 16 + lg * 4 + j;
      float inv = 1.0f / (zin[mt][j] + zi2[mt][j] + 1e-10f);
#pragma unroll
      for (int nt = 0; nt < 4; ++nt)
        ob[(size_t)t * 1024 + nt * 16 + ln] = f2b(o[mt][nt][j] * inv);
    }
}

// ---------------------------------------------------------------------------
extern "C" void kernel_launch(void* const* d_in, const int* in_sizes, int n_in,
                              void* d_out, int out_size, void* d_ws, size_t ws_size,
                              hipStream_t stream) {
  const float* hs    = (const float*)d_in[0];
  const float* Wq    = (const float*)d_in[1];
  const float* Wk    = (const float*)d_in[2];
  const float* Wv    = (const float*)d_in[3];
  const float* Wo    = (const float*)d_in[4];
  const float* gamma = (const float*)d_in[5];
  const float* beta  = (const float*)d_in[6];
  float* out = (float*)d_out;
  float* ws  = (float*)d_ws;

  unsigned short* QKB   = (unsigned short*)(ws + QK_OFF);
  unsigned short* VTg   = (unsigned short*)(ws + VT_OFF);
  unsigned short* Sraw  = (unsigned short*)(ws + SRAW_OFF);
  unsigned short* Spre  = (unsigned short*)(ws + SPRE_OFF);
  float* Mk = ws + MK_OFF;
  unsigned short* OAB   = (unsigned short*)(ws + OAB_OFF);
  unsigned short* WQKVB = (unsigned short*)(ws + WQKV_OFF);
  unsigned short* WOB   = (unsigned short*)(ws + WO_OFF);
  unsigned short* HSB   = (unsigned short*)(ws + HSB_OFF);

  dim3 blk(256);
  conv_all<<<5376, blk, 0, stream>>>(hs, Wq, Wk, Wv, Wo, HSB, WQKVB, WOB);
  proj_gemm<<<768, blk, 0, stream>>>(HSB, WQKVB, QKB, VTg);
  k_states<<<dim3(NCHUNK, NBH), blk, 0, stream>>>(QKB, VTg, gamma, beta, Sraw, Mk);
  k_prefix<<<dim3(9, NBH), blk, 0, stream>>>(Sraw, Spre, Mk);
  k_attn_out<<<dim3(NCHUNK, NBH), blk, 0, stream>>>(QKB, VTg, gamma, beta, Spre, Mk, OAB);
  out_gemm<<<512, blk, 0, stream>>>(OAB, WOB, out);
}